// Round 5
// baseline (641.923 us; speedup 1.0000x reference)
//
#include <hip/hip_runtime.h>
#include <stdint.h>

#define N_B    32768
#define MLPOUT 1056
#define MCAT_K 1216   // 1184 padded to 19*64
#define NPAD3  1280   // 1056 padded to 5*256

typedef __attribute__((ext_vector_type(8)))  __bf16 bf16x8;
typedef __attribute__((ext_vector_type(4)))  float  f32x4;
typedef __attribute__((ext_vector_type(16))) float  f32x16;

__device__ __forceinline__ uint16_t f2bf(float f){
  union { float f; uint32_t u; } v; v.f = f;
  return (uint16_t)((v.u + 0x7fffu + ((v.u >> 16) & 1u)) >> 16);
}
__device__ __forceinline__ float bf2f(uint16_t h){
  union { uint32_t u; float f; } v; v.u = ((uint32_t)h) << 16; return v.f;
}
__device__ __forceinline__ void gld_lds16(const void* gp, void* lp){
  __builtin_amdgcn_global_load_lds(
    (__attribute__((address_space(1))) void*)(void*)gp,
    (__attribute__((address_space(3))) void*)lp, 16, 0, 0);
}

// ---------------- k0a: f32 [K][N] -> bf16 [Npad][Kpad] transpose+cast+zero-pad ----------------
__global__ void transpose_cast_kernel(const float* __restrict__ in, uint16_t* __restrict__ out,
                                      int K, int N, int Kpad, int Npad)
{
  __shared__ float tile[32][33];
  const int tx = threadIdx.x & 31, ty = threadIdx.x >> 5;
  const int k0 = blockIdx.x * 32, n0 = blockIdx.y * 32;
#pragma unroll
  for (int i = 0; i < 4; i++){
    int k = k0 + ty + i*8, nn = n0 + tx;
    float v = (k < K && nn < N) ? in[(size_t)k*N + nn] : 0.0f;
    tile[ty + i*8][tx] = v;
  }
  __syncthreads();
#pragma unroll
  for (int i = 0; i < 4; i++){
    int nn = n0 + ty + i*8, k = k0 + tx;
    if (nn < Npad && k < Kpad) out[(size_t)nn*Kpad + k] = f2bf(tile[tx][ty + i*8]);
  }
}

// ---------------- k0b: fused W -> pre-packed MFMA B-fragments (hi/lo bf16) ----------------
__global__ void prep_small_kernel(const float* __restrict__ W_Z1, const float* __restrict__ W_Z2,
                                  const float* __restrict__ b3,
                                  uint16_t* __restrict__ WfH, uint16_t* __restrict__ WfL,
                                  float* __restrict__ wgG, float* __restrict__ b3p)
{
  __shared__ float wl[192*32];
  const int tid = threadIdx.x;
  for (int idx = tid; idx < 6144; idx += 256){
    int r = idx >> 5, c = idx & 31;
    float v;
    if (r < 64){
      v = 0.f;
      for (int i = 0; i < 32; i++) v += W_Z1[r*32 + i] * W_Z2[i*32 + c];
    } else v = W_Z2[(r - 32)*32 + c];
    wl[idx] = v;
  }
  __syncthreads();
  for (int q = tid; q < 768; q += 256){
    int lane = q & 63, ctkk = q >> 6;
    int ct = ctkk & 1, kk = ctkk >> 1;
    int c  = ct*16 + (lane & 15);
    int k0 = kk*32 + ((lane >> 4) << 3);
    for (int j = 0; j < 8; j++){
      float v = wl[(k0 + j)*32 + c];
      uint16_t hb = f2bf(v);
      WfH[q*8 + j] = hb;
      WfL[q*8 + j] = f2bf(v - bf2f(hb));
    }
  }
  if (tid < 32) wgG[tid] = W_Z2[160*32 + tid];
  for (int idx = tid; idx < NPAD3; idx += 256)
    b3p[idx] = (idx < MLPOUT) ? b3[idx] : 0.0f;
}

// ---------------- P1: h / hm / gate ----------------
__global__ __launch_bounds__(256)
void gate_kernel(const float* __restrict__ h0, const float* __restrict__ mh,
                 const float* __restrict__ W_h1, const float* __restrict__ b_h1,
                 const float* __restrict__ W_g1a, const float* __restrict__ b_g1a,
                 const float* __restrict__ W_g1b, const float* __restrict__ b_g1b,
                 uint16_t* __restrict__ Mcat, float* __restrict__ gateOut)
{
  __shared__ float wh[128*32];
  __shared__ float wg[160*32];
  __shared__ float wgb[32], bh[32], bga[32];
  __shared__ float bgb;
  __shared__ float hrow[4][128];
  __shared__ float hms[4][160];
  const int tid = threadIdx.x, w = tid >> 6, l = tid & 63;
  for (int i = tid; i < 4096; i += 256) wh[i] = W_h1[i];
  for (int i = tid; i < 5120; i += 256) wg[i] = W_g1a[i];
  if (tid < 32){ wgb[tid] = W_g1b[tid]; bh[tid] = b_h1[tid]; bga[tid] = b_g1a[tid]; }
  if (tid == 0) bgb = b_g1b[0];
  __syncthreads();
  const int cg = l & 31, kh = l >> 5;
  for (int bi = 0; bi < 16; bi++){
    const int b = blockIdx.x*64 + w*16 + bi;
    hrow[w][l]      = h0[(size_t)b*128 + l];
    hrow[w][64 + l] = h0[(size_t)b*128 + 64 + l];
    float mh0 = mh[(size_t)b*128 + l];
    float mh1 = mh[(size_t)b*128 + 64 + l];
    float hacc = 0.f;
#pragma unroll 16
    for (int i = 0; i < 64; i++){
      int k = kh*64 + i;
      hacc += hrow[w][k] * wh[k*32 + cg];
    }
    hacc += __shfl_xor(hacc, 32);
    float hmc = fmaxf(hacc + bh[cg], 0.f);
    float r0 = fmaxf(mh0, 0.f), r1 = fmaxf(mh1, 0.f);
    if (l < 32) hms[w][l] = hmc;
    hms[w][32 + l] = r0;
    hms[w][96 + l] = r1;
    uint16_t* mc = Mcat + (size_t)b*MCAT_K + 1024;
    if (l < 32) mc[l] = f2bf(hmc);
    mc[32 + l] = f2bf(r0);
    mc[96 + l] = f2bf(r1);
    if (l < 32) mc[160 + l] = 0;     // zero K-pad 1184..1215
    float tacc = 0.f;
#pragma unroll 16
    for (int i = 0; i < 80; i++){
      int k = kh*80 + i;
      tacc += hms[w][k] * wg[k*32 + cg];
    }
    tacc += __shfl_xor(tacc, 32);
    float tc = fmaxf(tacc + bga[cg], 0.f);
    float gp = (l < 32) ? tc * wgb[cg] : 0.f;
#pragma unroll
    for (int s = 1; s < 64; s <<= 1) gp += __shfl_xor(gp, s);
    if (l == 0) gateOut[b] = gp + bgb;
  }
}

// ---------------- P2: Zm (MFMA, compensated) + gram (MFMA) + F ----------------
__global__ __launch_bounds__(256)
void zm_gram_kernel(const float* __restrict__ Z0, const float* __restrict__ mZ,
                    const uint16_t* __restrict__ WfH, const uint16_t* __restrict__ WfL,
                    const float* __restrict__ wgG, const float* __restrict__ gateB,
                    uint16_t* __restrict__ Mcat, float* __restrict__ Fn,
                    float* __restrict__ ZmOut)
{
  __shared__ __align__(16) uint16_t wfh[6144], wfl[6144];
  __shared__ float wgs[32];
  __shared__ __align__(16) uint16_t zhS[4][32*24], zlS[4][32*24];
  const int tid = threadIdx.x, w = tid >> 6, l = tid & 63;
#pragma unroll
  for (int i = 0; i < 3; i++){
    gld_lds16(WfH + (i*256 + tid)*8, &wfh[(i*256 + w*64)*8]);
    gld_lds16(WfL + (i*256 + tid)*8, &wfl[(i*256 + w*64)*8]);
  }
  if (tid < 32) wgs[tid] = wgG[tid];
  __syncthreads();
  const int n = l & 15, sl = l >> 4;
  for (int bi = 0; bi < 4; bi++){
    const int b = (blockIdx.x << 4) + (w << 2) + bi;
    bf16x8 xh[6], xl[6];
    const float* zp = Z0 + (size_t)b*1024 + n*64  + sl*8;
    const float* mp = mZ + (size_t)b*2048 + n*128 + sl*8;
#pragma unroll
    for (int kk = 0; kk < 6; kk++){
      const float* src = (kk < 2) ? (zp + kk*32) : (mp + (kk - 2)*32);
      float x[8];
      *(float4*)&x[0] = *(const float4*)src;
      *(float4*)&x[4] = *(const float4*)(src + 4);
#pragma unroll
      for (int j = 0; j < 8; j++){
        __bf16 h = (__bf16)x[j];
        xh[kk][j] = h;
        xl[kk][j] = (__bf16)(x[j] - (float)h);
      }
    }
    f32x4 za[2];
    za[0] = (f32x4)(0.f); za[1] = (f32x4)(0.f);
#pragma unroll
    for (int kk = 0; kk < 6; kk++){
#pragma unroll
      for (int ct = 0; ct < 2; ct++){
        bf16x8 whf = *(const bf16x8*)&wfh[((kk*2 + ct)*64 + l)*8];
        bf16x8 wlf = *(const bf16x8*)&wfl[((kk*2 + ct)*64 + l)*8];
        za[ct] = __builtin_amdgcn_mfma_f32_16x16x32_bf16(xh[kk], whf, za[ct], 0, 0, 0);
        za[ct] = __builtin_amdgcn_mfma_f32_16x16x32_bf16(xl[kk], whf, za[ct], 0, 0, 0);
        za[ct] = __builtin_amdgcn_mfma_f32_16x16x32_bf16(xh[kk], wlf, za[ct], 0, 0, 0);
      }
    }
    const float g = gateB[b];
    if (sl == 0){
      za[0][2] += g * wgs[n];
      za[1][2] += g * wgs[16 + n];
    }
    float* zo = ZmOut + (size_t)b*512;
#pragma unroll
    for (int ct = 0; ct < 2; ct++){
      ushort4 ph, pl;
#pragma unroll
      for (int r = 0; r < 4; r++){
        float v = za[ct][r];
        zo[(sl*4 + r)*32 + ct*16 + n] = v;
        uint16_t hb = f2bf(v);
        ((uint16_t*)&ph)[r] = hb;
        ((uint16_t*)&pl)[r] = f2bf(v - bf2f(hb));
      }
      const int c = ct*16 + n;
      *(ushort4*)&zhS[w][c*24 + sl*4] = ph;
      *(ushort4*)&zlS[w][c*24 + sl*4] = pl;
    }
    const int c2 = l & 31, n0 = (l >> 5) << 3;
    bf16x8 zhf = *(const bf16x8*)&zhS[w][c2*24 + n0];
    bf16x8 zlf = *(const bf16x8*)&zlS[w][c2*24 + n0];
    f32x16 gacc = (f32x16)(0.f);
    gacc = __builtin_amdgcn_mfma_f32_32x32x16_bf16(zhf, zhf, gacc, 0, 0, 0);
    gacc = __builtin_amdgcn_mfma_f32_32x32x16_bf16(zlf, zhf, gacc, 0, 0, 0);
    gacc = __builtin_amdgcn_mfma_f32_32x32x16_bf16(zhf, zlf, gacc, 0, 0, 0);
    float fs = 0.f;
#pragma unroll
    for (int i = 0; i < 16; i++) fs += gacc[i]*gacc[i];
#pragma unroll
    for (int s = 1; s < 64; s <<= 1) fs += __shfl_xor(fs, s);
    if (l == 0) Fn[b] = sqrtf(fs) + 1.0f;
    uint16_t* mcb = Mcat + (size_t)b*MCAT_K;
#pragma unroll
    for (int r = 0; r < 16; r++){
      int row = (r & 3) + 8*(r >> 2) + 4*(l >> 5);
      mcb[row*32 + c2] = f2bf(gacc[r]);
    }
  }
}

// ---------------- fused 3-layer MLP: one block = one 128-row strip, 8 waves (2M x 4N) ----------------
// Per layer: A [rows][KK] bf16 (strip-local), Bt [256*NTN][KK] bf16.
// LDS per buf (24576 elems): A tile [128][64] (2 halves of 64 rows, 4096 elems each),
//                            B tile [256][64] (2 halves of 128 interleaved rows, 8192 elems each).
// Swizzle: 16B-chunk ^ (stage-slot-row & 7); staged linear, source pre-swizzled, read swizzled.
// Schedule per K-tile t (buf p=t&1): P0: read ALL frags + stage B-h1(t+1, other buf); MFMA(ns=0);
//                                    P1: stage A+B-h0(t+2, buf p); MFMA(ns=1); vmcnt(4).
template<int NT, int NTN, int RELU, int MODE>
__device__ __forceinline__ void gemm_layer(const uint16_t* __restrict__ A,
                                           const uint16_t* __restrict__ Bt,
                                           const float* __restrict__ bias,
                                           uint16_t* __restrict__ outB,
                                           float* __restrict__ outF,
                                           const float* __restrict__ Fn,
                                           uint16_t* lds, int m0)
{
  constexpr int KK = NT * 64;
  const int tid = threadIdx.x;
  const int w = tid >> 6, l = tid & 63;
  const int wr = w >> 2, wc = w & 3;
  const int rA = l & 15, kq = l >> 4;
  const int cs0 = ((kq)     ^ (rA & 7)) * 8;
  const int cs1 = ((4 + kq) ^ (rA & 7)) * 8;

#define STAGE_A_(base_, hf_, kt_) do{ \
    int r_ = tid >> 3, c_ = (tid & 7) ^ (r_ & 7); \
    gld_lds16(A + (size_t)(m0 + (hf_)*64 + r_)*KK + (kt_)*64 + c_*8, \
              &lds[(base_) + (hf_)*4096 + (w*64)*8]); }while(0)
#define STAGE_B_(base_, hf_, kt_) do{ \
  _Pragma("unroll") for (int j_ = 0; j_ < 2; j_++){ \
    int sl_ = j_*512 + tid; int r_ = sl_ >> 3; int c_ = (sl_ & 7) ^ (r_ & 7); \
    int rg_ = ((r_ >> 5) << 6) + (hf_)*32 + (r_ & 31); \
    gld_lds16(Bt + (size_t)(nb + rg_)*KK + (kt_)*64 + c_*8, \
              &lds[(base_) + 8192 + (hf_)*8192 + (j_*512 + w*64)*8]); } }while(0)
#define RD_A_(base_) do{ _Pragma("unroll") for (int mf_ = 0; mf_ < 4; mf_++){ \
    int ro_ = (base_) + (wr*64 + mf_*16 + rA)*64; \
    aF[mf_][0] = *(const uint4*)&lds[ro_ + cs0]; \
    aF[mf_][1] = *(const uint4*)&lds[ro_ + cs1]; } }while(0)
#define RD_B_(dst_, base_, ns_) do{ _Pragma("unroll") for (int gg_ = 0; gg_ < 2; gg_++){ \
    int ro_ = (base_) + 8192 + (ns_)*8192 + (wc*32 + gg_*16 + rA)*64; \
    dst_[gg_][0] = *(const uint4*)&lds[ro_ + cs0]; \
    dst_[gg_][1] = *(const uint4*)&lds[ro_ + cs1]; } }while(0)
#define MFMA16_(ns_, B_) do{ _Pragma("unroll") for (int mf_ = 0; mf_ < 4; mf_++) \
  _Pragma("unroll") for (int gg_ = 0; gg_ < 2; gg_++){ \
    acc[mf_][(ns_)*2+gg_] = __builtin_amdgcn_mfma_f32_16x16x32_bf16( \
      __builtin_bit_cast(bf16x8, aF[mf_][0]), __builtin_bit_cast(bf16x8, B_[gg_][0]), \
      acc[mf_][(ns_)*2+gg_], 0, 0, 0); \
    acc[mf_][(ns_)*2+gg_] = __builtin_amdgcn_mfma_f32_16x16x32_bf16( \
      __builtin_bit_cast(bf16x8, aF[mf_][1]), __builtin_bit_cast(bf16x8, B_[gg_][1]), \
      acc[mf_][(ns_)*2+gg_], 0, 0, 0); } }while(0)

#pragma unroll 1
  for (int nt = 0; nt < NTN; nt++){
    const int nb = nt * 256;
    f32x4 acc[4][4];
#pragma unroll
    for (int mf = 0; mf < 4; mf++)
#pragma unroll
      for (int q = 0; q < 4; q++) acc[mf][q] = (f32x4)(0.0f);
    uint4 aF[4][2], bF0[2][2], bF1[2][2];

    // prologue: tile0 full (6 loads) + tile1 A,B-h0 (4 loads); tile1 B-h1 staged at t=0 P0
    STAGE_A_(0, 0, 0); STAGE_A_(0, 1, 0); STAGE_B_(0, 0, 0); STAGE_B_(0, 1, 0);
    STAGE_A_(24576, 0, 1); STAGE_A_(24576, 1, 1); STAGE_B_(24576, 0, 1);
    asm volatile("s_waitcnt vmcnt(4)" ::: "memory");
    __builtin_amdgcn_s_barrier();

#pragma unroll 1
    for (int t = 0; t < NT; t++){
      const int pb = (t & 1) ? 24576 : 0;
      const int ob = 24576 - pb;
      // ---- P0: all fragment reads + B-h1 prefetch for t+1 ----
      RD_A_(pb);
      RD_B_(bF0, pb, 0);
      RD_B_(bF1, pb, 1);
      if (t + 1 < NT) STAGE_B_(ob, 1, t + 1);
      __builtin_amdgcn_s_barrier();
      __builtin_amdgcn_s_setprio(1);
      MFMA16_(0, bF0);
      __builtin_amdgcn_s_setprio(0);
      __builtin_amdgcn_s_barrier();
      // ---- P1: A + B-h0 prefetch for t+2 (same buf; reads completed in P0) ----
      if (t + 2 < NT){ STAGE_A_(pb, 0, t + 2); STAGE_A_(pb, 1, t + 2); STAGE_B_(pb, 0, t + 2); }
      __builtin_amdgcn_s_barrier();
      __builtin_amdgcn_s_setprio(1);
      MFMA16_(1, bF1);
      __builtin_amdgcn_s_setprio(0);
      if (t < NT - 2)       { asm volatile("s_waitcnt vmcnt(4)" ::: "memory"); }
      else if (t == NT - 2) { asm volatile("s_waitcnt vmcnt(0)" ::: "memory"); }
      __builtin_amdgcn_s_barrier();
    }

    // ---- epilogue: C/D col = rA, row = kq*4 + i ----
#pragma unroll
    for (int mf = 0; mf < 4; mf++){
      const int grow0 = m0 + wr*64 + mf*16 + kq*4;
#pragma unroll
      for (int q = 0; q < 4; q++){
        const int gcol = nb + wc*64 + q*16 + rA;
        const float bv = bias[gcol];
#pragma unroll
        for (int i = 0; i < 4; i++){
          float v = acc[mf][q][i] + bv;
          if (RELU) v = fmaxf(v, 0.0f);
          const int grow = grow0 + i;
          if (MODE == 0){
            outB[(size_t)grow*1024 + gcol] = f2bf(v);
          } else {
            if (gcol < 1024)      outB[(size_t)grow*1024 + gcol] = f2bf(v);
            else if (gcol < 1056) outF[(size_t)grow*32 + (gcol - 1024)] = v / Fn[grow];
          }
        }
      }
    }
  }
#undef STAGE_A_
#undef STAGE_B_
#undef RD_A_
#undef RD_B_
#undef MFMA16_
}

__global__ __launch_bounds__(512, 2)
void mlp_fused_kernel(const uint16_t* __restrict__ Mcat, const uint16_t* __restrict__ W1t,
                      const float* __restrict__ b1, uint16_t* __restrict__ H1,
                      const uint16_t* __restrict__ W2t, const float* __restrict__ b2,
                      uint16_t* __restrict__ H2, const uint16_t* __restrict__ W3t,
                      const float* __restrict__ b3p, uint16_t* __restrict__ Mzf,
                      float* __restrict__ OutMH, const float* __restrict__ Fn)
{
  __shared__ __align__(16) uint16_t lds[49152];   // 96 KiB -> 1 block/CU
  const int m0 = blockIdx.x * 128;
  gemm_layer<19, 4, 1, 0>(Mcat, W1t, b1, H1, nullptr, nullptr, lds, m0);
  asm volatile("s_waitcnt vmcnt(0) lgkmcnt(0)" ::: "memory");
  __threadfence();
  __syncthreads();
  gemm_layer<16, 4, 1, 0>(H1, W2t, b2, H2, nullptr, nullptr, lds, m0);
  asm volatile("s_waitcnt vmcnt(0) lgkmcnt(0)" ::: "memory");
  __threadfence();
  __syncthreads();
  gemm_layer<16, 5, 0, 1>(H2, W3t, b3p, Mzf, OutMH, Fn, lds, m0);
}

// ---------------- k5: M_Z = (Zm @ M_Zflat) / F ----------------
__global__ __launch_bounds__(256)
void epilogue_kernel(const uint16_t* __restrict__ Mzf, const float* __restrict__ Fn,
                     float* __restrict__ Out)
{
  __shared__ __align__(16) uint16_t mzS[4][1024];
  __shared__ __align__(16) float    zmS[4][16*36];
  const int tid = threadIdx.x, w = tid >> 6, l = tid & 63;
  const int n = l & 15, q = l >> 4;
  for (int bi = 0; bi < 4; bi++){
    const int b = (blockIdx.x << 4) + (w << 2) + bi;
    const uint4* src = (const uint4*)(Mzf + (size_t)b*1024);
    uint4* dst = (uint4*)&mzS[w][0];
    dst[l]      = src[l];
    dst[l + 64] = src[l + 64];
    const float4* zsrc = (const float4*)(Out + (size_t)b*512);
#pragma unroll
    for (int i = 0; i < 2; i++){
      int f = i*64 + l;
      int nn = f >> 3, c4 = f & 7;
      *(float4*)&zmS[w][nn*36 + c4*4] = zsrc[f];
    }
    float acc[8];
#pragma unroll
    for (int i = 0; i < 8; i++) acc[i] = 0.f;
#pragma unroll
    for (int j = 0; j < 32; j++){
      float zv = zmS[w][n*36 + j];
      uint4 mv = *(const uint4*)&mzS[w][j*32 + q*8];
      acc[0] += zv * bf2f((uint16_t)(mv.x & 0xffffu));
      acc[1] += zv * bf2f((uint16_t)(mv.x >> 16));
      acc[2] += zv * bf2f((uint16_t)(mv.y & 0xffffu));
      acc[3] += zv * bf2f((uint16_t)(mv.y >> 16));
      acc[4] += zv * bf2f((uint16_t)(mv.z & 0xffffu));
      acc[5] += zv * bf2f((uint16_t)(mv.z >> 16));
      acc[6] += zv * bf2f((uint16_t)(mv.w & 0xffffu));
      acc[7] += zv * bf2f((uint16_t)(mv.w >> 16));
    }
    const float inv = 1.0f / Fn[b];
    float4* op = (float4*)(Out + (size_t)b*512 + n*32 + q*8);
    op[0] = make_float4(acc[0]*inv, acc[1]*inv, acc[2]*inv, acc[3]*inv);
    op[1] = make_float4(acc[4]*inv, acc[5]*inv, acc[6]*inv, acc[7]*inv);
  }
}

// ---------------- launch ----------------
extern "C" void kernel_launch(void* const* d_in, const int* in_sizes, int n_in,
                              void* d_out, int out_size, void* d_ws, size_t ws_size,
                              hipStream_t stream)
{
  const float* Z0    = (const float*)d_in[0];
  const float* h0    = (const float*)d_in[1];
  const float* mZ    = (const float*)d_in[2];
  const float* mh    = (const float*)d_in[3];
  const float* W_Z1  = (const float*)d_in[4];
  const float* W_h1  = (const float*)d_in[5];
  const float* b_h1  = (const float*)d_in[6];
  const float* W_g1a = (const float*)d_in[7];
  const float* b_g1a = (const float*)d_in[8];
  const float* W_g1b = (const float*)d_in[9];
  const float* b_g1b = (const float*)d_in[10];
  const float* W_Z2  = (const float*)d_in[11];
  const float* W1    = (const float*)d_in[12];
  const float* b1    = (const float*)d_in[13];
  const float* W2    = (const float*)d_in[14];
  const float* b2    = (const float*)d_in[15];
  const float* W3    = (const float*)d_in[16];
  const float* b3    = (const float*)d_in[17];

  char* ws = (char*)d_ws;
  size_t off = 0;
  auto alloc = [&](size_t bytes) -> char* {
    char* p = ws + off;
    off += (bytes + 255) & ~(size_t)255;
    return p;
  };
  uint16_t* W1t  = (uint16_t*)alloc((size_t)1024*MCAT_K*2);
  uint16_t* W2t  = (uint16_t*)alloc((size_t)1024*1024*2);
  uint16_t* W3t  = (uint16_t*)alloc((size_t)NPAD3*1024*2);
  float*    b3p  = (float*)   alloc((size_t)NPAD3*4);
  uint16_t* WfH  = (uint16_t*)alloc((size_t)6144*2);
  uint16_t* WfL  = (uint16_t*)alloc((size_t)6144*2);
  float*    wgG  = (float*)   alloc((size_t)32*4);
  float*    gate = (float*)   alloc((size_t)N_B*4);
  float*    Fn   = (float*)   alloc((size_t)N_B*4);
  uint16_t* Mcat = (uint16_t*)alloc((size_t)N_B*MCAT_K*2);
  uint16_t* H1   = (uint16_t*)alloc((size_t)N_B*1024*2);
  uint16_t* H2   = (uint16_t*)alloc((size_t)N_B*1024*2);
  uint16_t* Mzf  = Mcat;   // layer-3 out overwrites Mcat rows already consumed by layer 1 (block-local)
  float* OutMZ = (float*)d_out;
  float* OutMH = (float*)d_out + (size_t)N_B*512;

  transpose_cast_kernel<<<dim3(38,32), 256, 0, stream>>>(W1, W1t, 1184, 1024, MCAT_K, 1024);
  transpose_cast_kernel<<<dim3(32,32), 256, 0, stream>>>(W2, W2t, 1024, 1024, 1024, 1024);
  transpose_cast_kernel<<<dim3(32,40), 256, 0, stream>>>(W3, W3t, 1024, 1056, 1024, NPAD3);
  prep_small_kernel<<<1, 256, 0, stream>>>(W_Z1, W_Z2, b3, WfH, WfL, wgG, b3p);
  gate_kernel<<<512, 256, 0, stream>>>(h0, mh, W_h1, b_h1, W_g1a, b_g1a, W_g1b, b_g1b,
                                       Mcat, gate);
  zm_gram_kernel<<<2048, 256, 0, stream>>>(Z0, mZ, WfH, WfL, wgG, gate, Mcat, Fn, OutMZ);
  mlp_fused_kernel<<<256, 512, 0, stream>>>(Mcat, W1t, b1, H1, W2t, b2, H2,
                                            W3t, b3p, Mzf, OutMH, Fn);
  epilogue_kernel<<<2048, 256, 0, stream>>>(Mzf, Fn, OutMZ);
}

// Round 6
// 557.822 us; speedup vs baseline: 1.1508x; 1.1508x over previous
//
#include <hip/hip_runtime.h>
#include <stdint.h>

#define N_B    32768
#define MLPOUT 1056
#define MCAT_K 1216   // 1184 padded to 19*64
#define NPAD3  1280   // 1056 padded to 5*256

typedef __attribute__((ext_vector_type(8)))  __bf16 bf16x8;
typedef __attribute__((ext_vector_type(4)))  float  f32x4;
typedef __attribute__((ext_vector_type(16))) float  f32x16;

__device__ __forceinline__ uint16_t f2bf(float f){
  union { float f; uint32_t u; } v; v.f = f;
  return (uint16_t)((v.u + 0x7fffu + ((v.u >> 16) & 1u)) >> 16);
}
__device__ __forceinline__ float bf2f(uint16_t h){
  union { uint32_t u; float f; } v; v.u = ((uint32_t)h) << 16; return v.f;
}
__device__ __forceinline__ void gld_lds16(const void* gp, void* lp){
  __builtin_amdgcn_global_load_lds(
    (__attribute__((address_space(1))) void*)(void*)gp,
    (__attribute__((address_space(3))) void*)lp, 16, 0, 0);
}

// ---------------- k0a: f32 [K][N] -> bf16 [Npad][Kpad] transpose+cast+zero-pad ----------------
__global__ void transpose_cast_kernel(const float* __restrict__ in, uint16_t* __restrict__ out,
                                      int K, int N, int Kpad, int Npad)
{
  __shared__ float tile[32][33];
  const int tx = threadIdx.x & 31, ty = threadIdx.x >> 5;
  const int k0 = blockIdx.x * 32, n0 = blockIdx.y * 32;
#pragma unroll
  for (int i = 0; i < 4; i++){
    int k = k0 + ty + i*8, nn = n0 + tx;
    float v = (k < K && nn < N) ? in[(size_t)k*N + nn] : 0.0f;
    tile[ty + i*8][tx] = v;
  }
  __syncthreads();
#pragma unroll
  for (int i = 0; i < 4; i++){
    int nn = n0 + ty + i*8, k = k0 + tx;
    if (nn < Npad && k < Kpad) out[(size_t)nn*Kpad + k] = f2bf(tile[tx][ty + i*8]);
  }
}

// ---------------- k0b: fused W -> pre-packed MFMA B-fragments (hi/lo bf16) ----------------
__global__ void prep_small_kernel(const float* __restrict__ W_Z1, const float* __restrict__ W_Z2,
                                  const float* __restrict__ b3,
                                  uint16_t* __restrict__ WfH, uint16_t* __restrict__ WfL,
                                  float* __restrict__ wgG, float* __restrict__ b3p)
{
  __shared__ float wl[192*32];
  const int tid = threadIdx.x;
  for (int idx = tid; idx < 6144; idx += 256){
    int r = idx >> 5, c = idx & 31;
    float v;
    if (r < 64){
      v = 0.f;
      for (int i = 0; i < 32; i++) v += W_Z1[r*32 + i] * W_Z2[i*32 + c];
    } else v = W_Z2[(r - 32)*32 + c];
    wl[idx] = v;
  }
  __syncthreads();
  for (int q = tid; q < 768; q += 256){
    int lane = q & 63, ctkk = q >> 6;
    int ct = ctkk & 1, kk = ctkk >> 1;
    int c  = ct*16 + (lane & 15);
    int k0 = kk*32 + ((lane >> 4) << 3);
    for (int j = 0; j < 8; j++){
      float v = wl[(k0 + j)*32 + c];
      uint16_t hb = f2bf(v);
      WfH[q*8 + j] = hb;
      WfL[q*8 + j] = f2bf(v - bf2f(hb));
    }
  }
  if (tid < 32) wgG[tid] = W_Z2[160*32 + tid];
  for (int idx = tid; idx < NPAD3; idx += 256)
    b3p[idx] = (idx < MLPOUT) ? b3[idx] : 0.0f;
}

// ---------------- P1: h / hm / gate ----------------
__global__ __launch_bounds__(256)
void gate_kernel(const float* __restrict__ h0, const float* __restrict__ mh,
                 const float* __restrict__ W_h1, const float* __restrict__ b_h1,
                 const float* __restrict__ W_g1a, const float* __restrict__ b_g1a,
                 const float* __restrict__ W_g1b, const float* __restrict__ b_g1b,
                 uint16_t* __restrict__ Mcat, float* __restrict__ gateOut)
{
  __shared__ float wh[128*32];
  __shared__ float wg[160*32];
  __shared__ float wgb[32], bh[32], bga[32];
  __shared__ float bgb;
  __shared__ float hrow[4][128];
  __shared__ float hms[4][160];
  const int tid = threadIdx.x, w = tid >> 6, l = tid & 63;
  for (int i = tid; i < 4096; i += 256) wh[i] = W_h1[i];
  for (int i = tid; i < 5120; i += 256) wg[i] = W_g1a[i];
  if (tid < 32){ wgb[tid] = W_g1b[tid]; bh[tid] = b_h1[tid]; bga[tid] = b_g1a[tid]; }
  if (tid == 0) bgb = b_g1b[0];
  __syncthreads();
  const int cg = l & 31, kh = l >> 5;
  for (int bi = 0; bi < 16; bi++){
    const int b = blockIdx.x*64 + w*16 + bi;
    hrow[w][l]      = h0[(size_t)b*128 + l];
    hrow[w][64 + l] = h0[(size_t)b*128 + 64 + l];
    float mh0 = mh[(size_t)b*128 + l];
    float mh1 = mh[(size_t)b*128 + 64 + l];
    float hacc = 0.f;
#pragma unroll 16
    for (int i = 0; i < 64; i++){
      int k = kh*64 + i;
      hacc += hrow[w][k] * wh[k*32 + cg];
    }
    hacc += __shfl_xor(hacc, 32);
    float hmc = fmaxf(hacc + bh[cg], 0.f);
    float r0 = fmaxf(mh0, 0.f), r1 = fmaxf(mh1, 0.f);
    if (l < 32) hms[w][l] = hmc;
    hms[w][32 + l] = r0;
    hms[w][96 + l] = r1;
    uint16_t* mc = Mcat + (size_t)b*MCAT_K + 1024;
    if (l < 32) mc[l] = f2bf(hmc);
    mc[32 + l] = f2bf(r0);
    mc[96 + l] = f2bf(r1);
    if (l < 32) mc[160 + l] = 0;     // zero K-pad 1184..1215
    float tacc = 0.f;
#pragma unroll 16
    for (int i = 0; i < 80; i++){
      int k = kh*80 + i;
      tacc += hms[w][k] * wg[k*32 + cg];
    }
    tacc += __shfl_xor(tacc, 32);
    float tc = fmaxf(tacc + bga[cg], 0.f);
    float gp = (l < 32) ? tc * wgb[cg] : 0.f;
#pragma unroll
    for (int s = 1; s < 64; s <<= 1) gp += __shfl_xor(gp, s);
    if (l == 0) gateOut[b] = gp + bgb;
  }
}

// ---------------- P2: Zm (MFMA, compensated) + gram (MFMA) + F ----------------
__global__ __launch_bounds__(256)
void zm_gram_kernel(const float* __restrict__ Z0, const float* __restrict__ mZ,
                    const uint16_t* __restrict__ WfH, const uint16_t* __restrict__ WfL,
                    const float* __restrict__ wgG, const float* __restrict__ gateB,
                    uint16_t* __restrict__ Mcat, float* __restrict__ Fn,
                    float* __restrict__ ZmOut)
{
  __shared__ __align__(16) uint16_t wfh[6144], wfl[6144];
  __shared__ float wgs[32];
  __shared__ __align__(16) uint16_t zhS[4][32*24], zlS[4][32*24];
  const int tid = threadIdx.x, w = tid >> 6, l = tid & 63;
#pragma unroll
  for (int i = 0; i < 3; i++){
    gld_lds16(WfH + (i*256 + tid)*8, &wfh[(i*256 + w*64)*8]);
    gld_lds16(WfL + (i*256 + tid)*8, &wfl[(i*256 + w*64)*8]);
  }
  if (tid < 32) wgs[tid] = wgG[tid];
  __syncthreads();
  const int n = l & 15, sl = l >> 4;
  for (int bi = 0; bi < 4; bi++){
    const int b = (blockIdx.x << 4) + (w << 2) + bi;
    bf16x8 xh[6], xl[6];
    const float* zp = Z0 + (size_t)b*1024 + n*64  + sl*8;
    const float* mp = mZ + (size_t)b*2048 + n*128 + sl*8;
#pragma unroll
    for (int kk = 0; kk < 6; kk++){
      const float* src = (kk < 2) ? (zp + kk*32) : (mp + (kk - 2)*32);
      float x[8];
      *(float4*)&x[0] = *(const float4*)src;
      *(float4*)&x[4] = *(const float4*)(src + 4);
#pragma unroll
      for (int j = 0; j < 8; j++){
        __bf16 h = (__bf16)x[j];
        xh[kk][j] = h;
        xl[kk][j] = (__bf16)(x[j] - (float)h);
      }
    }
    f32x4 za[2];
    za[0] = (f32x4)(0.f); za[1] = (f32x4)(0.f);
#pragma unroll
    for (int kk = 0; kk < 6; kk++){
#pragma unroll
      for (int ct = 0; ct < 2; ct++){
        bf16x8 whf = *(const bf16x8*)&wfh[((kk*2 + ct)*64 + l)*8];
        bf16x8 wlf = *(const bf16x8*)&wfl[((kk*2 + ct)*64 + l)*8];
        za[ct] = __builtin_amdgcn_mfma_f32_16x16x32_bf16(xh[kk], whf, za[ct], 0, 0, 0);
        za[ct] = __builtin_amdgcn_mfma_f32_16x16x32_bf16(xl[kk], whf, za[ct], 0, 0, 0);
        za[ct] = __builtin_amdgcn_mfma_f32_16x16x32_bf16(xh[kk], wlf, za[ct], 0, 0, 0);
      }
    }
    const float g = gateB[b];
    if (sl == 0){
      za[0][2] += g * wgs[n];
      za[1][2] += g * wgs[16 + n];
    }
    float* zo = ZmOut + (size_t)b*512;
#pragma unroll
    for (int ct = 0; ct < 2; ct++){
      ushort4 ph, pl;
#pragma unroll
      for (int r = 0; r < 4; r++){
        float v = za[ct][r];
        zo[(sl*4 + r)*32 + ct*16 + n] = v;
        uint16_t hb = f2bf(v);
        ((uint16_t*)&ph)[r] = hb;
        ((uint16_t*)&pl)[r] = f2bf(v - bf2f(hb));
      }
      const int c = ct*16 + n;
      *(ushort4*)&zhS[w][c*24 + sl*4] = ph;
      *(ushort4*)&zlS[w][c*24 + sl*4] = pl;
    }
    const int c2 = l & 31, n0 = (l >> 5) << 3;
    bf16x8 zhf = *(const bf16x8*)&zhS[w][c2*24 + n0];
    bf16x8 zlf = *(const bf16x8*)&zlS[w][c2*24 + n0];
    f32x16 gacc = (f32x16)(0.f);
    gacc = __builtin_amdgcn_mfma_f32_32x32x16_bf16(zhf, zhf, gacc, 0, 0, 0);
    gacc = __builtin_amdgcn_mfma_f32_32x32x16_bf16(zlf, zhf, gacc, 0, 0, 0);
    gacc = __builtin_amdgcn_mfma_f32_32x32x16_bf16(zhf, zlf, gacc, 0, 0, 0);
    float fs = 0.f;
#pragma unroll
    for (int i = 0; i < 16; i++) fs += gacc[i]*gacc[i];
#pragma unroll
    for (int s = 1; s < 64; s <<= 1) fs += __shfl_xor(fs, s);
    if (l == 0) Fn[b] = sqrtf(fs) + 1.0f;
    uint16_t* mcb = Mcat + (size_t)b*MCAT_K;
#pragma unroll
    for (int r = 0; r < 16; r++){
      int row = (r & 3) + 8*(r >> 2) + 4*(l >> 5);
      mcb[row*32 + c2] = f2bf(gacc[r]);
    }
  }
}

// ---------------- 256x256 8-phase bf16 GEMM ----------------
// A [M][KK] bf16, Bt [Ntiles*256][KK] bf16. NT = KK/64 K-tiles.
// KEY CHANGE r6: raw inline-asm s_barrier (compiler cannot attach vmcnt(0) drains to an asm
// block; __builtin_amdgcn_s_barrier was suspected of being decorated with full waitcnt drains,
// killing the counted-vmcnt pipeline). Counted-wait ledger re-verified: vmcnt(6) at end of
// tile t-1 leaves exactly {A0,B0,A1}[t+1] in flight => all of tile t's halves landed.
template<int NT, int RELU, int MODE, int NTN>
__global__ __launch_bounds__(512, 1)
void gemm8p_kernel(const uint16_t* __restrict__ A, const uint16_t* __restrict__ Bt,
                   const float* __restrict__ bias, uint16_t* __restrict__ outB,
                   float* __restrict__ outF, const float* __restrict__ Fn)
{
  constexpr int KK   = NT * 64;
  constexpr int NWG8 = (128 * NTN) / 8;
  __shared__ __align__(16) uint16_t lds[65536];   // 128 KiB: [buf][A/B][half][128*64]
  const int tid = threadIdx.x;
  const int w = tid >> 6, l = tid & 63;
  const int wr = w >> 2, wc = w & 3;
  const int rA = l & 15, kq = l >> 4, swz = rA & 7;
  const int wr64 = wr * 64, wc32 = wc * 32;
  const int cs0 = ((kq)     ^ swz) * 8;
  const int cs1 = ((4 + kq) ^ swz) * 8;
  // XCD-contiguous remap: XCD x owns consecutive m-groups x all n (A-panel L2 reuse)
  const int bid = blockIdx.x;
  const int tl  = (bid & 7) * NWG8 + (bid >> 3);
  const int m0  = (tl / NTN) * 256, n0 = (tl % NTN) * 256;

  f32x4 acc[8][4];
#pragma unroll
  for (int f = 0; f < 8; f++)
#pragma unroll
    for (int g = 0; g < 4; g++) acc[f][g] = (f32x4)(0.0f);
  uint4 aF[4][2], bF0[2][2], bF1[2][2];

#define STAGE_A(bf_, hf_, kt_) do{ \
  _Pragma("unroll") for (int j_ = 0; j_ < 2; j_++){ \
    int sl_ = j_*512 + tid; int r_ = sl_ >> 3; int c_ = (sl_ & 7) ^ (r_ & 7); \
    int rg_ = ((r_ >> 6) << 7) + (hf_)*64 + (r_ & 63); \
    gld_lds16(A + (size_t)(m0 + rg_)*KK + (kt_)*64 + c_*8, \
              &lds[(bf_)*32768 + (hf_)*8192 + (j_*512 + w*64)*8]); } }while(0)
#define STAGE_B(bf_, hf_, kt_) do{ \
  _Pragma("unroll") for (int j_ = 0; j_ < 2; j_++){ \
    int sl_ = j_*512 + tid; int r_ = sl_ >> 3; int c_ = (sl_ & 7) ^ (r_ & 7); \
    int rg_ = ((r_ >> 5) << 6) + (hf_)*32 + (r_ & 31); \
    gld_lds16(Bt + (size_t)(n0 + rg_)*KK + (kt_)*64 + c_*8, \
              &lds[(bf_)*32768 + 16384 + (hf_)*8192 + (j_*512 + w*64)*8]); } }while(0)
#define RD_A(bf_, hf_) do{ _Pragma("unroll") for (int ff_ = 0; ff_ < 4; ff_++){ \
    int ro_ = (bf_)*32768 + (hf_)*8192 + (wr64 + ff_*16 + rA)*64; \
    aF[ff_][0] = *(const uint4*)&lds[ro_ + cs0]; \
    aF[ff_][1] = *(const uint4*)&lds[ro_ + cs1]; } }while(0)
#define RD_B(dst_, bf_, hf_) do{ _Pragma("unroll") for (int gg_ = 0; gg_ < 2; gg_++){ \
    int ro_ = (bf_)*32768 + 16384 + (hf_)*8192 + (wc32 + gg_*16 + rA)*64; \
    dst_[gg_][0] = *(const uint4*)&lds[ro_ + cs0]; \
    dst_[gg_][1] = *(const uint4*)&lds[ro_ + cs1]; } }while(0)
#define MFMA16(ms_, ns_, B_) do{ _Pragma("unroll") for (int ff_ = 0; ff_ < 4; ff_++) \
  _Pragma("unroll") for (int gg_ = 0; gg_ < 2; gg_++){ \
    acc[(ms_)*4+ff_][(ns_)*2+gg_] = __builtin_amdgcn_mfma_f32_16x16x32_bf16( \
      __builtin_bit_cast(bf16x8, aF[ff_][0]), __builtin_bit_cast(bf16x8, B_[gg_][0]), \
      acc[(ms_)*4+ff_][(ns_)*2+gg_], 0, 0, 0); \
    acc[(ms_)*4+ff_][(ns_)*2+gg_] = __builtin_amdgcn_mfma_f32_16x16x32_bf16( \
      __builtin_bit_cast(bf16x8, aF[ff_][1]), __builtin_bit_cast(bf16x8, B_[gg_][1]), \
      acc[(ms_)*4+ff_][(ns_)*2+gg_], 0, 0, 0); } }while(0)
#define BAR()   asm volatile("s_barrier" ::: "memory")
#define LGKM0() asm volatile("s_waitcnt lgkmcnt(0)" ::: "memory")
#define PRIO1() __builtin_amdgcn_s_setprio(1)
#define PRIO0() __builtin_amdgcn_s_setprio(0)

  // prologue: tile0 h0..h3 (8 loads) + tile1 h0,h1,h2 (6 loads); wait 8 oldest -> tile0 landed
  STAGE_A(0, 0, 0); STAGE_B(0, 0, 0); STAGE_A(0, 1, 0); STAGE_B(0, 1, 0);
  STAGE_A(1, 0, 1); STAGE_B(1, 0, 1); STAGE_A(1, 1, 1);
  asm volatile("s_waitcnt vmcnt(6)" ::: "memory");
  BAR();

  // one K-tile, compile-time LDS buffer parity BUF_, runtime tile index t_
#define ITER(BUF_, t_) do{ \
    RD_A(BUF_, 0); RD_B(bF0, BUF_, 0); \
    if ((t_) + 1 < NT) STAGE_B(1 - (BUF_), 1, (t_) + 1); \
    BAR(); LGKM0(); \
    PRIO1(); MFMA16(0, 0, bF0); PRIO0(); \
    BAR(); \
    RD_B(bF1, BUF_, 1); \
    if ((t_) + 2 < NT) STAGE_A(BUF_, 0, (t_) + 2); \
    BAR(); LGKM0(); \
    PRIO1(); MFMA16(0, 1, bF1); PRIO0(); \
    BAR(); \
    RD_A(BUF_, 1); \
    if ((t_) + 2 < NT) STAGE_B(BUF_, 0, (t_) + 2); \
    BAR(); LGKM0(); \
    PRIO1(); MFMA16(1, 0, bF0); PRIO0(); \
    BAR(); \
    if ((t_) + 2 < NT) STAGE_A(BUF_, 1, (t_) + 2); \
    BAR(); \
    PRIO1(); MFMA16(1, 1, bF1); PRIO0(); \
    if ((t_) < NT - 2)       { asm volatile("s_waitcnt vmcnt(6)" ::: "memory"); } \
    else if ((t_) == NT - 2) { asm volatile("s_waitcnt vmcnt(0)" ::: "memory"); } \
    BAR(); \
  }while(0)

#pragma unroll 1
  for (int t = 0; t + 1 < NT; t += 2){
    ITER(0, t);
    ITER(1, t + 1);
  }
  if (NT & 1) ITER(0, NT - 1);

#undef ITER
#undef STAGE_A
#undef STAGE_B
#undef RD_A
#undef RD_B
#undef MFMA16
#undef BAR
#undef LGKM0
#undef PRIO1
#undef PRIO0

  // epilogue: C/D layout col = l&15, row = (l>>4)*4 + i
#pragma unroll
  for (int f = 0; f < 8; f++){
    int grow0 = m0 + wr*128 + f*16 + kq*4;
#pragma unroll
    for (int g = 0; g < 4; g++){
      int gcol = n0 + wc*64 + g*16 + rA;
      float bv = bias[gcol];
#pragma unroll
      for (int i = 0; i < 4; i++){
        float v = acc[f][g][i] + bv;
        if (RELU) v = fmaxf(v, 0.0f);
        int grow = grow0 + i;
        if (MODE == 0){
          outB[(size_t)grow*1024 + gcol] = f2bf(v);
        } else {
          if (gcol < 1024)      outB[(size_t)grow*1024 + gcol] = f2bf(v);
          else if (gcol < 1056) outF[(size_t)grow*32 + (gcol - 1024)] = v / Fn[grow];
        }
      }
    }
  }
}

// ---------------- k5: M_Z = (Zm @ M_Zflat) / F ----------------
__global__ __launch_bounds__(256)
void epilogue_kernel(const uint16_t* __restrict__ Mzf, const float* __restrict__ Fn,
                     float* __restrict__ Out)
{
  __shared__ __align__(16) uint16_t mzS[4][1024];
  __shared__ __align__(16) float    zmS[4][16*36];
  const int tid = threadIdx.x, w = tid >> 6, l = tid & 63;
  const int n = l & 15, q = l >> 4;
  for (int bi = 0; bi < 4; bi++){
    const int b = (blockIdx.x << 4) + (w << 2) + bi;
    const uint4* src = (const uint4*)(Mzf + (size_t)b*1024);
    uint4* dst = (uint4*)&mzS[w][0];
    dst[l]      = src[l];
    dst[l + 64] = src[l + 64];
    const float4* zsrc = (const float4*)(Out + (size_t)b*512);
#pragma unroll
    for (int i = 0; i < 2; i++){
      int f = i*64 + l;
      int nn = f >> 3, c4 = f & 7;
      *(float4*)&zmS[w][nn*36 + c4*4] = zsrc[f];
    }
    float acc[8];
#pragma unroll
    for (int i = 0; i < 8; i++) acc[i] = 0.f;
#pragma unroll
    for (int j = 0; j < 32; j++){
      float zv = zmS[w][n*36 + j];
      uint4 mv = *(const uint4*)&mzS[w][j*32 + q*8];
      acc[0] += zv * bf2f((uint16_t)(mv.x & 0xffffu));
      acc[1] += zv * bf2f((uint16_t)(mv.x >> 16));
      acc[2] += zv * bf2f((uint16_t)(mv.y & 0xffffu));
      acc[3] += zv * bf2f((uint16_t)(mv.y >> 16));
      acc[4] += zv * bf2f((uint16_t)(mv.z & 0xffffu));
      acc[5] += zv * bf2f((uint16_t)(mv.z >> 16));
      acc[6] += zv * bf2f((uint16_t)(mv.w & 0xffffu));
      acc[7] += zv * bf2f((uint16_t)(mv.w >> 16));
    }
    const float inv = 1.0f / Fn[b];
    float4* op = (float4*)(Out + (size_t)b*512 + n*32 + q*8);
    op[0] = make_float4(acc[0]*inv, acc[1]*inv, acc[2]*inv, acc[3]*inv);
    op[1] = make_float4(acc[4]*inv, acc[5]*inv, acc[6]*inv, acc[7]*inv);
  }
}

// ---------------- launch ----------------
extern "C" void kernel_launch(void* const* d_in, const int* in_sizes, int n_in,
                              void* d_out, int out_size, void* d_ws, size_t ws_size,
                              hipStream_t stream)
{
  const float* Z0    = (const float*)d_in[0];
  const float* h0    = (const float*)d_in[1];
  const float* mZ    = (const float*)d_in[2];
  const float* mh    = (const float*)d_in[3];
  const float* W_Z1  = (const float*)d_in[4];
  const float* W_h1  = (const float*)d_in[5];
  const float* b_h1  = (const float*)d_in[6];
  const float* W_g1a = (const float*)d_in[7];
  const float* b_g1a = (const float*)d_in[8];
  const float* W_g1b = (const float*)d_in[9];
  const float* b_g1b = (const float*)d_in[10];
  const float* W_Z2  = (const float*)d_in[11];
  const float* W1    = (const float*)d_in[12];
  const float* b1    = (const float*)d_in[13];
  const float* W2    = (const float*)d_in[14];
  const float* b2    = (const float*)d_in[15];
  const float* W3    = (const float*)d_in[16];
  const float* b3    = (const float*)d_in[17];

  char* ws = (char*)d_ws;
  size_t off = 0;
  auto alloc = [&](size_t bytes) -> char* {
    char* p = ws + off;
    off += (bytes + 255) & ~(size_t)255;
    return p;
  };
  uint16_t* W1t  = (uint16_t*)alloc((size_t)1024*MCAT_K*2);
  uint16_t* W2t  = (uint16_t*)alloc((size_t)1024*1024*2);
  uint16_t* W3t  = (uint16_t*)alloc((size_t)NPAD3*1024*2);
  float*    b3p  = (float*)   alloc((size_t)NPAD3*4);
  uint16_t* WfH  = (uint16_t*)alloc((size_t)6144*2);
  uint16_t* WfL  = (uint16_t*)alloc((size_t)6144*2);
  float*    wgG  = (float*)   alloc((size_t)32*4);
  float*    gate = (float*)   alloc((size_t)N_B*4);
  float*    Fn   = (float*)   alloc((size_t)N_B*4);
  uint16_t* Mcat = (uint16_t*)alloc((size_t)N_B*MCAT_K*2);
  uint16_t* H1   = (uint16_t*)alloc((size_t)N_B*1024*2);
  uint16_t* H2   = (uint16_t*)alloc((size_t)N_B*1024*2);
  uint16_t* Mzf  = Mcat;                          // Mcat dead after GEMM1 -> reuse (stride 1024)
  float* OutMZ = (float*)d_out;
  float* OutMH = (float*)d_out + (size_t)N_B*512;

  transpose_cast_kernel<<<dim3(38,32), 256, 0, stream>>>(W1, W1t, 1184, 1024, MCAT_K, 1024);
  transpose_cast_kernel<<<dim3(32,32), 256, 0, stream>>>(W2, W2t, 1024, 1024, 1024, 1024);
  transpose_cast_kernel<<<dim3(32,40), 256, 0, stream>>>(W3, W3t, 1024, 1056, 1024, NPAD3);
  prep_small_kernel<<<1, 256, 0, stream>>>(W_Z1, W_Z2, b3, WfH, WfL, wgG, b3p);
  gate_kernel<<<512, 256, 0, stream>>>(h0, mh, W_h1, b_h1, W_g1a, b_g1a, W_g1b, b_g1b,
                                       Mcat, gate);
  zm_gram_kernel<<<2048, 256, 0, stream>>>(Z0, mZ, WfH, WfL, wgG, gate, Mcat, Fn, OutMZ);
  gemm8p_kernel<19,1,0,4><<<512, 512, 0, stream>>>(Mcat, W1t, b1, H1, nullptr, nullptr);
  gemm8p_kernel<16,1,0,4><<<512, 512, 0, stream>>>(H1,   W2t, b2, H2, nullptr, nullptr);
  gemm8p_kernel<16,0,1,5><<<640, 512, 0, stream>>>(H2,   W3t, b3p, Mzf, OutMH, Fn);
  epilogue_kernel<<<2048, 256, 0, stream>>>(Mzf, Fn, OutMZ);
}

// Round 7
// 542.260 us; speedup vs baseline: 1.1838x; 1.0287x over previous
//
#include <hip/hip_runtime.h>
#include <stdint.h>

#define N_B    32768
#define MLPOUT 1056
#define MCAT_K 1216   // 1184 padded to 19*64
#define NPAD3  1280   // 1056 padded to 5*256

typedef __attribute__((ext_vector_type(8)))  __bf16 bf16x8;
typedef __attribute__((ext_vector_type(4)))  float  f32x4;
typedef __attribute__((ext_vector_type(16))) float  f32x16;

__device__ __forceinline__ uint16_t f2bf(float f){
  union { float f; uint32_t u; } v; v.f = f;
  return (uint16_t)((v.u + 0x7fffu + ((v.u >> 16) & 1u)) >> 16);
}
__device__ __forceinline__ float bf2f(uint16_t h){
  union { uint32_t u; float f; } v; v.u = ((uint32_t)h) << 16; return v.f;
}
__device__ __forceinline__ void gld_lds16(const void* gp, void* lp){
  __builtin_amdgcn_global_load_lds(
    (__attribute__((address_space(1))) void*)(void*)gp,
    (__attribute__((address_space(3))) void*)lp, 16, 0, 0);
}

// ---------------- k0a: f32 [K][N] -> bf16 [Npad][Kpad] transpose+cast+zero-pad ----------------
__global__ void transpose_cast_kernel(const float* __restrict__ in, uint16_t* __restrict__ out,
                                      int K, int N, int Kpad, int Npad)
{
  __shared__ float tile[32][33];
  const int tx = threadIdx.x & 31, ty = threadIdx.x >> 5;
  const int k0 = blockIdx.x * 32, n0 = blockIdx.y * 32;
#pragma unroll
  for (int i = 0; i < 4; i++){
    int k = k0 + ty + i*8, nn = n0 + tx;
    float v = (k < K && nn < N) ? in[(size_t)k*N + nn] : 0.0f;
    tile[ty + i*8][tx] = v;
  }
  __syncthreads();
#pragma unroll
  for (int i = 0; i < 4; i++){
    int nn = n0 + ty + i*8, k = k0 + tx;
    if (nn < Npad && k < Kpad) out[(size_t)nn*Kpad + k] = f2bf(tile[tx][ty + i*8]);
  }
}

// ---------------- k0b: fused W -> pre-packed MFMA B-fragments (hi/lo bf16) ----------------
__global__ void prep_small_kernel(const float* __restrict__ W_Z1, const float* __restrict__ W_Z2,
                                  const float* __restrict__ b3,
                                  uint16_t* __restrict__ WfH, uint16_t* __restrict__ WfL,
                                  float* __restrict__ wgG, float* __restrict__ b3p)
{
  __shared__ float wl[192*32];
  const int tid = threadIdx.x;
  for (int idx = tid; idx < 6144; idx += 256){
    int r = idx >> 5, c = idx & 31;
    float v;
    if (r < 64){
      v = 0.f;
      for (int i = 0; i < 32; i++) v += W_Z1[r*32 + i] * W_Z2[i*32 + c];
    } else v = W_Z2[(r - 32)*32 + c];
    wl[idx] = v;
  }
  __syncthreads();
  for (int q = tid; q < 768; q += 256){
    int lane = q & 63, ctkk = q >> 6;
    int ct = ctkk & 1, kk = ctkk >> 1;
    int c  = ct*16 + (lane & 15);
    int k0 = kk*32 + ((lane >> 4) << 3);
    for (int j = 0; j < 8; j++){
      float v = wl[(k0 + j)*32 + c];
      uint16_t hb = f2bf(v);
      WfH[q*8 + j] = hb;
      WfL[q*8 + j] = f2bf(v - bf2f(hb));
    }
  }
  if (tid < 32) wgG[tid] = W_Z2[160*32 + tid];
  for (int idx = tid; idx < NPAD3; idx += 256)
    b3p[idx] = (idx < MLPOUT) ? b3[idx] : 0.0f;
}

// ---------------- P1: h / hm / gate ----------------
__global__ __launch_bounds__(256)
void gate_kernel(const float* __restrict__ h0, const float* __restrict__ mh,
                 const float* __restrict__ W_h1, const float* __restrict__ b_h1,
                 const float* __restrict__ W_g1a, const float* __restrict__ b_g1a,
                 const float* __restrict__ W_g1b, const float* __restrict__ b_g1b,
                 uint16_t* __restrict__ Mcat, float* __restrict__ gateOut)
{
  __shared__ float wh[128*32];
  __shared__ float wg[160*32];
  __shared__ float wgb[32], bh[32], bga[32];
  __shared__ float bgb;
  __shared__ float hrow[4][128];
  __shared__ float hms[4][160];
  const int tid = threadIdx.x, w = tid >> 6, l = tid & 63;
  for (int i = tid; i < 4096; i += 256) wh[i] = W_h1[i];
  for (int i = tid; i < 5120; i += 256) wg[i] = W_g1a[i];
  if (tid < 32){ wgb[tid] = W_g1b[tid]; bh[tid] = b_h1[tid]; bga[tid] = b_g1a[tid]; }
  if (tid == 0) bgb = b_g1b[0];
  __syncthreads();
  const int cg = l & 31, kh = l >> 5;
  for (int bi = 0; bi < 16; bi++){
    const int b = blockIdx.x*64 + w*16 + bi;
    hrow[w][l]      = h0[(size_t)b*128 + l];
    hrow[w][64 + l] = h0[(size_t)b*128 + 64 + l];
    float mh0 = mh[(size_t)b*128 + l];
    float mh1 = mh[(size_t)b*128 + 64 + l];
    float hacc = 0.f;
#pragma unroll 16
    for (int i = 0; i < 64; i++){
      int k = kh*64 + i;
      hacc += hrow[w][k] * wh[k*32 + cg];
    }
    hacc += __shfl_xor(hacc, 32);
    float hmc = fmaxf(hacc + bh[cg], 0.f);
    float r0 = fmaxf(mh0, 0.f), r1 = fmaxf(mh1, 0.f);
    if (l < 32) hms[w][l] = hmc;
    hms[w][32 + l] = r0;
    hms[w][96 + l] = r1;
    uint16_t* mc = Mcat + (size_t)b*MCAT_K + 1024;
    if (l < 32) mc[l] = f2bf(hmc);
    mc[32 + l] = f2bf(r0);
    mc[96 + l] = f2bf(r1);
    if (l < 32) mc[160 + l] = 0;     // zero K-pad 1184..1215
    float tacc = 0.f;
#pragma unroll 16
    for (int i = 0; i < 80; i++){
      int k = kh*80 + i;
      tacc += hms[w][k] * wg[k*32 + cg];
    }
    tacc += __shfl_xor(tacc, 32);
    float tc = fmaxf(tacc + bga[cg], 0.f);
    float gp = (l < 32) ? tc * wgb[cg] : 0.f;
#pragma unroll
    for (int s = 1; s < 64; s <<= 1) gp += __shfl_xor(gp, s);
    if (l == 0) gateOut[b] = gp + bgb;
  }
}

// ---------------- P2: Zm (MFMA, compensated) + gram (MFMA) + F ----------------
__global__ __launch_bounds__(256)
void zm_gram_kernel(const float* __restrict__ Z0, const float* __restrict__ mZ,
                    const uint16_t* __restrict__ WfH, const uint16_t* __restrict__ WfL,
                    const float* __restrict__ wgG, const float* __restrict__ gateB,
                    uint16_t* __restrict__ Mcat, float* __restrict__ Fn,
                    float* __restrict__ ZmOut)
{
  __shared__ __align__(16) uint16_t wfh[6144], wfl[6144];
  __shared__ float wgs[32];
  __shared__ __align__(16) uint16_t zhS[4][32*24], zlS[4][32*24];
  const int tid = threadIdx.x, w = tid >> 6, l = tid & 63;
#pragma unroll
  for (int i = 0; i < 3; i++){
    gld_lds16(WfH + (i*256 + tid)*8, &wfh[(i*256 + w*64)*8]);
    gld_lds16(WfL + (i*256 + tid)*8, &wfl[(i*256 + w*64)*8]);
  }
  if (tid < 32) wgs[tid] = wgG[tid];
  __syncthreads();
  const int n = l & 15, sl = l >> 4;
  for (int bi = 0; bi < 4; bi++){
    const int b = (blockIdx.x << 4) + (w << 2) + bi;
    bf16x8 xh[6], xl[6];
    const float* zp = Z0 + (size_t)b*1024 + n*64  + sl*8;
    const float* mp = mZ + (size_t)b*2048 + n*128 + sl*8;
#pragma unroll
    for (int kk = 0; kk < 6; kk++){
      const float* src = (kk < 2) ? (zp + kk*32) : (mp + (kk - 2)*32);
      float x[8];
      *(float4*)&x[0] = *(const float4*)src;
      *(float4*)&x[4] = *(const float4*)(src + 4);
#pragma unroll
      for (int j = 0; j < 8; j++){
        __bf16 h = (__bf16)x[j];
        xh[kk][j] = h;
        xl[kk][j] = (__bf16)(x[j] - (float)h);
      }
    }
    f32x4 za[2];
    za[0] = (f32x4)(0.f); za[1] = (f32x4)(0.f);
#pragma unroll
    for (int kk = 0; kk < 6; kk++){
#pragma unroll
      for (int ct = 0; ct < 2; ct++){
        bf16x8 whf = *(const bf16x8*)&wfh[((kk*2 + ct)*64 + l)*8];
        bf16x8 wlf = *(const bf16x8*)&wfl[((kk*2 + ct)*64 + l)*8];
        za[ct] = __builtin_amdgcn_mfma_f32_16x16x32_bf16(xh[kk], whf, za[ct], 0, 0, 0);
        za[ct] = __builtin_amdgcn_mfma_f32_16x16x32_bf16(xl[kk], whf, za[ct], 0, 0, 0);
        za[ct] = __builtin_amdgcn_mfma_f32_16x16x32_bf16(xh[kk], wlf, za[ct], 0, 0, 0);
      }
    }
    const float g = gateB[b];
    if (sl == 0){
      za[0][2] += g * wgs[n];
      za[1][2] += g * wgs[16 + n];
    }
    float* zo = ZmOut + (size_t)b*512;
#pragma unroll
    for (int ct = 0; ct < 2; ct++){
      ushort4 ph, pl;
#pragma unroll
      for (int r = 0; r < 4; r++){
        float v = za[ct][r];
        zo[(sl*4 + r)*32 + ct*16 + n] = v;
        uint16_t hb = f2bf(v);
        ((uint16_t*)&ph)[r] = hb;
        ((uint16_t*)&pl)[r] = f2bf(v - bf2f(hb));
      }
      const int c = ct*16 + n;
      *(ushort4*)&zhS[w][c*24 + sl*4] = ph;
      *(ushort4*)&zlS[w][c*24 + sl*4] = pl;
    }
    const int c2 = l & 31, n0 = (l >> 5) << 3;
    bf16x8 zhf = *(const bf16x8*)&zhS[w][c2*24 + n0];
    bf16x8 zlf = *(const bf16x8*)&zlS[w][c2*24 + n0];
    f32x16 gacc = (f32x16)(0.f);
    gacc = __builtin_amdgcn_mfma_f32_32x32x16_bf16(zhf, zhf, gacc, 0, 0, 0);
    gacc = __builtin_amdgcn_mfma_f32_32x32x16_bf16(zlf, zhf, gacc, 0, 0, 0);
    gacc = __builtin_amdgcn_mfma_f32_32x32x16_bf16(zhf, zlf, gacc, 0, 0, 0);
    float fs = 0.f;
#pragma unroll
    for (int i = 0; i < 16; i++) fs += gacc[i]*gacc[i];
#pragma unroll
    for (int s = 1; s < 64; s <<= 1) fs += __shfl_xor(fs, s);
    if (l == 0) Fn[b] = sqrtf(fs) + 1.0f;
    uint16_t* mcb = Mcat + (size_t)b*MCAT_K;
#pragma unroll
    for (int r = 0; r < 16; r++){
      int row = (r & 3) + 8*(r >> 2) + 4*(l >> 5);
      mcb[row*32 + c2] = f2bf(gacc[r]);
    }
  }
}

// ---------------- 256x256 bf16 GEMM, minimal-barrier K-loop ----------------
// A [M][KK] bf16, Bt [Ntiles*256][KK] bf16. NT = KK/64 K-tiles.
// r7: ONE s_barrier + ONE vmcnt(0) per K-tile. Per tile: issue all 8 global_load_lds for
// t+1 (other buf) FIRST, then compiler-scheduled ds_reads + 64 MFMA from current buf
// (hipcc inserts fine-grained lgkmcnt; wave0's MFMA overlaps waves1-7's LDS drain),
// then vmcnt(0) (residual only) + s_barrier. No setprio, no manual lgkm, no sched_barrier.
template<int NT, int RELU, int MODE, int NTN>
__global__ __launch_bounds__(512, 1)
void gemm8p_kernel(const uint16_t* __restrict__ A, const uint16_t* __restrict__ Bt,
                   const float* __restrict__ bias, uint16_t* __restrict__ outB,
                   float* __restrict__ outF, const float* __restrict__ Fn)
{
  constexpr int KK   = NT * 64;
  constexpr int NWG8 = (128 * NTN) / 8;
  __shared__ __align__(16) uint16_t lds[65536];   // 128 KiB: [buf][A/B][half][128*64]
  const int tid = threadIdx.x;
  const int w = tid >> 6, l = tid & 63;
  const int wr = w >> 2, wc = w & 3;
  const int rA = l & 15, kq = l >> 4, swz = rA & 7;
  const int wr64 = wr * 64, wc32 = wc * 32;
  const int cs0 = ((kq)     ^ swz) * 8;
  const int cs1 = ((4 + kq) ^ swz) * 8;
  // XCD-contiguous remap: XCD x owns consecutive m-groups x all n (A-panel L2 reuse)
  const int bid = blockIdx.x;
  const int tl  = (bid & 7) * NWG8 + (bid >> 3);
  const int m0  = (tl / NTN) * 256, n0 = (tl % NTN) * 256;

  f32x4 acc[8][4];
#pragma unroll
  for (int f = 0; f < 8; f++)
#pragma unroll
    for (int g = 0; g < 4; g++) acc[f][g] = (f32x4)(0.0f);
  uint4 aF[4][2], bF0[2][2], bF1[2][2];

#define STAGE_A(bf_, hf_, kt_) do{ \
  _Pragma("unroll") for (int j_ = 0; j_ < 2; j_++){ \
    int sl_ = j_*512 + tid; int r_ = sl_ >> 3; int c_ = (sl_ & 7) ^ (r_ & 7); \
    int rg_ = ((r_ >> 6) << 7) + (hf_)*64 + (r_ & 63); \
    gld_lds16(A + (size_t)(m0 + rg_)*KK + (kt_)*64 + c_*8, \
              &lds[(bf_)*32768 + (hf_)*8192 + (j_*512 + w*64)*8]); } }while(0)
#define STAGE_B(bf_, hf_, kt_) do{ \
  _Pragma("unroll") for (int j_ = 0; j_ < 2; j_++){ \
    int sl_ = j_*512 + tid; int r_ = sl_ >> 3; int c_ = (sl_ & 7) ^ (r_ & 7); \
    int rg_ = ((r_ >> 5) << 6) + (hf_)*32 + (r_ & 31); \
    gld_lds16(Bt + (size_t)(n0 + rg_)*KK + (kt_)*64 + c_*8, \
              &lds[(bf_)*32768 + 16384 + (hf_)*8192 + (j_*512 + w*64)*8]); } }while(0)
#define RD_A(bf_, hf_) do{ _Pragma("unroll") for (int ff_ = 0; ff_ < 4; ff_++){ \
    int ro_ = (bf_)*32768 + (hf_)*8192 + (wr64 + ff_*16 + rA)*64; \
    aF[ff_][0] = *(const uint4*)&lds[ro_ + cs0]; \
    aF[ff_][1] = *(const uint4*)&lds[ro_ + cs1]; } }while(0)
#define RD_B(dst_, bf_, hf_) do{ _Pragma("unroll") for (int gg_ = 0; gg_ < 2; gg_++){ \
    int ro_ = (bf_)*32768 + 16384 + (hf_)*8192 + (wc32 + gg_*16 + rA)*64; \
    dst_[gg_][0] = *(const uint4*)&lds[ro_ + cs0]; \
    dst_[gg_][1] = *(const uint4*)&lds[ro_ + cs1]; } }while(0)
#define MFMA16(ms_, ns_, B_) do{ _Pragma("unroll") for (int ff_ = 0; ff_ < 4; ff_++) \
  _Pragma("unroll") for (int gg_ = 0; gg_ < 2; gg_++){ \
    acc[(ms_)*4+ff_][(ns_)*2+gg_] = __builtin_amdgcn_mfma_f32_16x16x32_bf16( \
      __builtin_bit_cast(bf16x8, aF[ff_][0]), __builtin_bit_cast(bf16x8, B_[gg_][0]), \
      acc[(ms_)*4+ff_][(ns_)*2+gg_], 0, 0, 0); \
    acc[(ms_)*4+ff_][(ns_)*2+gg_] = __builtin_amdgcn_mfma_f32_16x16x32_bf16( \
      __builtin_bit_cast(bf16x8, aF[ff_][1]), __builtin_bit_cast(bf16x8, B_[gg_][1]), \
      acc[(ms_)*4+ff_][(ns_)*2+gg_], 0, 0, 0); } }while(0)
#define BAR()   asm volatile("s_barrier" ::: "memory")

  // prologue: stage tile 0 into buf 0, drain, barrier
  STAGE_A(0, 0, 0); STAGE_A(0, 1, 0); STAGE_B(0, 0, 0); STAGE_B(0, 1, 0);
  asm volatile("s_waitcnt vmcnt(0)" ::: "memory");
  BAR();

  // one K-tile: prefetch t+1 (other buf) -> compute t -> vmcnt(0) -> barrier
#define ITER2(BUF_, t_) do{ \
    if ((t_) + 1 < NT){ \
      STAGE_A(1 - (BUF_), 0, (t_) + 1); STAGE_A(1 - (BUF_), 1, (t_) + 1); \
      STAGE_B(1 - (BUF_), 0, (t_) + 1); STAGE_B(1 - (BUF_), 1, (t_) + 1); \
    } \
    RD_B(bF0, BUF_, 0); RD_B(bF1, BUF_, 1); \
    RD_A(BUF_, 0); \
    MFMA16(0, 0, bF0); MFMA16(0, 1, bF1); \
    RD_A(BUF_, 1); \
    MFMA16(1, 0, bF0); MFMA16(1, 1, bF1); \
    if ((t_) + 1 < NT){ asm volatile("s_waitcnt vmcnt(0)" ::: "memory"); } \
    BAR(); \
  }while(0)

#pragma unroll 1
  for (int t = 0; t + 1 < NT; t += 2){
    ITER2(0, t);
    ITER2(1, t + 1);
  }
  if (NT & 1) ITER2(0, NT - 1);

#undef ITER2
#undef STAGE_A
#undef STAGE_B
#undef RD_A
#undef RD_B
#undef MFMA16
#undef BAR

  // epilogue: C/D layout col = l&15, row = (l>>4)*4 + i
#pragma unroll
  for (int f = 0; f < 8; f++){
    int grow0 = m0 + wr*128 + f*16 + kq*4;
#pragma unroll
    for (int g = 0; g < 4; g++){
      int gcol = n0 + wc*64 + g*16 + rA;
      float bv = bias[gcol];
#pragma unroll
      for (int i = 0; i < 4; i++){
        float v = acc[f][g][i] + bv;
        if (RELU) v = fmaxf(v, 0.0f);
        int grow = grow0 + i;
        if (MODE == 0){
          outB[(size_t)grow*1024 + gcol] = f2bf(v);
        } else {
          if (gcol < 1024)      outB[(size_t)grow*1024 + gcol] = f2bf(v);
          else if (gcol < 1056) outF[(size_t)grow*32 + (gcol - 1024)] = v / Fn[grow];
        }
      }
    }
  }
}

// ---------------- k5: M_Z = (Zm @ M_Zflat) / F ----------------
__global__ __launch_bounds__(256)
void epilogue_kernel(const uint16_t* __restrict__ Mzf, const float* __restrict__ Fn,
                     float* __restrict__ Out)
{
  __shared__ __align__(16) uint16_t mzS[4][1024];
  __shared__ __align__(16) float    zmS[4][16*36];
  const int tid = threadIdx.x, w = tid >> 6, l = tid & 63;
  const int n = l & 15, q = l >> 4;
  for (int bi = 0; bi < 4; bi++){
    const int b = (blockIdx.x << 4) + (w << 2) + bi;
    const uint4* src = (const uint4*)(Mzf + (size_t)b*1024);
    uint4* dst = (uint4*)&mzS[w][0];
    dst[l]      = src[l];
    dst[l + 64] = src[l + 64];
    const float4* zsrc = (const float4*)(Out + (size_t)b*512);
#pragma unroll
    for (int i = 0; i < 2; i++){
      int f = i*64 + l;
      int nn = f >> 3, c4 = f & 7;
      *(float4*)&zmS[w][nn*36 + c4*4] = zsrc[f];
    }
    float acc[8];
#pragma unroll
    for (int i = 0; i < 8; i++) acc[i] = 0.f;
#pragma unroll
    for (int j = 0; j < 32; j++){
      float zv = zmS[w][n*36 + j];
      uint4 mv = *(const uint4*)&mzS[w][j*32 + q*8];
      acc[0] += zv * bf2f((uint16_t)(mv.x & 0xffffu));
      acc[1] += zv * bf2f((uint16_t)(mv.x >> 16));
      acc[2] += zv * bf2f((uint16_t)(mv.y & 0xffffu));
      acc[3] += zv * bf2f((uint16_t)(mv.y >> 16));
      acc[4] += zv * bf2f((uint16_t)(mv.z & 0xffffu));
      acc[5] += zv * bf2f((uint16_t)(mv.z >> 16));
      acc[6] += zv * bf2f((uint16_t)(mv.w & 0xffffu));
      acc[7] += zv * bf2f((uint16_t)(mv.w >> 16));
    }
    const float inv = 1.0f / Fn[b];
    float4* op = (float4*)(Out + (size_t)b*512 + n*32 + q*8);
    op[0] = make_float4(acc[0]*inv, acc[1]*inv, acc[2]*inv, acc[3]*inv);
    op[1] = make_float4(acc[4]*inv, acc[5]*inv, acc[6]*inv, acc[7]*inv);
  }
}

// ---------------- launch ----------------
extern "C" void kernel_launch(void* const* d_in, const int* in_sizes, int n_in,
                              void* d_out, int out_size, void* d_ws, size_t ws_size,
                              hipStream_t stream)
{
  const float* Z0    = (const float*)d_in[0];
  const float* h0    = (const float*)d_in[1];
  const float* mZ    = (const float*)d_in[2];
  const float* mh    = (const float*)d_in[3];
  const float* W_Z1  = (const float*)d_in[4];
  const float* W_h1  = (const float*)d_in[5];
  const float* b_h1  = (const float*)d_in[6];
  const float* W_g1a = (const float*)d_in[7];
  const float* b_g1a = (const float*)d_in[8];
  const float* W_g1b = (const float*)d_in[9];
  const float* b_g1b = (const float*)d_in[10];
  const float* W_Z2  = (const float*)d_in[11];
  const float* W1    = (const float*)d_in[12];
  const float* b1    = (const float*)d_in[13];
  const float* W2    = (const float*)d_in[14];
  const float* b2    = (const float*)d_in[15];
  const float* W3    = (const float*)d_in[16];
  const float* b3    = (const float*)d_in[17];

  char* ws = (char*)d_ws;
  size_t off = 0;
  auto alloc = [&](size_t bytes) -> char* {
    char* p = ws + off;
    off += (bytes + 255) & ~(size_t)255;
    return p;
  };
  uint16_t* W1t  = (uint16_t*)alloc((size_t)1024*MCAT_K*2);
  uint16_t* W2t  = (uint16_t*)alloc((size_t)1024*1024*2);
  uint16_t* W3t  = (uint16_t*)alloc((size_t)NPAD3*1024*2);
  float*    b3p  = (float*)   alloc((size_t)NPAD3*4);
  uint16_t* WfH  = (uint16_t*)alloc((size_t)6144*2);
  uint16_t* WfL  = (uint16_t*)alloc((size_t)6144*2);
  float*    wgG  = (float*)   alloc((size_t)32*4);
  float*    gate = (float*)   alloc((size_t)N_B*4);
  float*    Fn   = (float*)   alloc((size_t)N_B*4);
  uint16_t* Mcat = (uint16_t*)alloc((size_t)N_B*MCAT_K*2);
  uint16_t* H1   = (uint16_t*)alloc((size_t)N_B*1024*2);
  uint16_t* H2   = (uint16_t*)alloc((size_t)N_B*1024*2);
  uint16_t* Mzf  = Mcat;                          // Mcat dead after GEMM1 -> reuse (stride 1024)
  float* OutMZ = (float*)d_out;
  float* OutMH = (float*)d_out + (size_t)N_B*512;

  transpose_cast_kernel<<<dim3(38,32), 256, 0, stream>>>(W1, W1t, 1184, 1024, MCAT_K, 1024);
  transpose_cast_kernel<<<dim3(32,32), 256, 0, stream>>>(W2, W2t, 1024, 1024, 1024, 1024);
  transpose_cast_kernel<<<dim3(32,40), 256, 0, stream>>>(W3, W3t, 1024, 1056, 1024, NPAD3);
  prep_small_kernel<<<1, 256, 0, stream>>>(W_Z1, W_Z2, b3, WfH, WfL, wgG, b3p);
  gate_kernel<<<512, 256, 0, stream>>>(h0, mh, W_h1, b_h1, W_g1a, b_g1a, W_g1b, b_g1b,
                                       Mcat, gate);
  zm_gram_kernel<<<2048, 256, 0, stream>>>(Z0, mZ, WfH, WfL, wgG, gate, Mcat, Fn, OutMZ);
  gemm8p_kernel<19,1,0,4><<<512, 512, 0, stream>>>(Mcat, W1t, b1, H1, nullptr, nullptr);
  gemm8p_kernel<16,1,0,4><<<512, 512, 0, stream>>>(H1,   W2t, b2, H2, nullptr, nullptr);
  gemm8p_kernel<16,0,1,5><<<640, 512, 0, stream>>>(H2,   W3t, b3p, Mzf, OutMH, Fn);
  epilogue_kernel<<<2048, 256, 0, stream>>>(Mzf, Fn, OutMZ);
}